// Round 1
// baseline (911.481 us; speedup 1.0000x reference)
//
#include <hip/hip_runtime.h>
#include <math.h>

#define Bn 8
#define Cn 10
#define Hd 384
#define Wd 384
#define HW (Hd*Wd)          // 147456
#define TX 32
#define TY 8
#define TLX 36              // TX + 4 halo
#define TLY 12              // TY + 4 halo
#define TSZ (TLX*TLY)       // 432
#define BLOCKS_PER_IMG 576  // HW/256
#define TILES_X 12          // 384/32

// ---------------- Kernel A: softmax + neighborhood features ----------------
__global__ __launch_bounds__(256) void kA(const float* __restrict__ x,
                                          float* __restrict__ fout) {
    __shared__ float Pt[Cn * TSZ];
    const int bid = blockIdx.x;
    const int b   = bid / BLOCKS_PER_IMG;
    const int t   = bid % BLOCKS_PER_IMG;
    const int ty  = t / TILES_X, tx = t % TILES_X;
    const int x0  = tx * TX, y0 = ty * TY;
    const int tid = threadIdx.x;
    const float* xb = x + b * Cn * HW;

    // Load halo'd tile, computing softmax per position. Replicate padding ==
    // clamped coordinates.
    for (int i = tid; i < TSZ; i += 256) {
        int ly = i / TLX, lx = i % TLX;
        int gy = y0 + ly - 2; gy = max(0, min(Hd - 1, gy));
        int gx = x0 + lx - 2; gx = max(0, min(Wd - 1, gx));
        const float* px = xb + gy * Wd + gx;
        float v[Cn];
        float m = -1e30f;
        #pragma unroll
        for (int c = 0; c < Cn; c++) { v[c] = px[c * HW]; m = fmaxf(m, v[c]); }
        float s = 0.f;
        #pragma unroll
        for (int c = 0; c < Cn; c++) { v[c] = __expf(v[c] - m); s += v[c]; }
        float inv = 1.0f / s;
        #pragma unroll
        for (int c = 0; c < Cn; c++) Pt[c * TSZ + i] = v[c] * inv;
    }
    __syncthreads();

    const int lx = tid % TX, ly = tid / TX;
    float match3 = 0.f, ent3 = 0.f, var3 = 0.f, maj3 = -1e30f;
    float match5 = 0.f, ent5 = 0.f, var5 = 0.f, maj5 = -1e30f;

    #pragma unroll 1
    for (int c = 0; c < Cn; c++) {
        const float* Pc = &Pt[c * TSZ + (ly + 2) * TLX + (lx + 2)];
        float S5 = 0.f, S3 = 0.f, Q5 = 0.f, Q3 = 0.f;
        #pragma unroll
        for (int dy = -2; dy <= 2; dy++) {
            #pragma unroll
            for (int dx = -2; dx <= 2; dx++) {
                float v = Pc[dy * TLX + dx];
                S5 += v; Q5 += v * v;
                if (dy >= -1 && dy <= 1 && dx >= -1 && dx <= 1) {
                    S3 += v; Q3 += v * v;
                }
            }
        }
        float pc = Pc[0];
        match3 += pc * (S3 - pc);
        match5 += pc * (S5 - pc);
        maj3 = fmaxf(maj3, S3);
        maj5 = fmaxf(maj5, S5);
        float q3 = fmaxf(S3 * (1.f / 9.f), 1e-8f);  ent3 -= q3 * __logf(q3);
        float q5 = fmaxf(S5 * (1.f / 25.f), 1e-8f); ent5 -= q5 * __logf(q5);
        float pb3 = S3 * (1.f / 9.f);  var3 += Q3 * (1.f / 9.f)  - pb3 * pb3;
        float pb5 = S5 * (1.f / 25.f); var5 += Q5 * (1.f / 25.f) - pb5 * pb5;
    }

    const float invlogC = 1.0f / 2.302585092994046f; // 1/ln(10)
    float f0 = match3 * (1.f / 8.f);
    float f1 = maj3 * (1.f / 9.f);
    float f2 = 1.f - ent3 * invlogC;
    float f3 = var3;
    float f4 = match5 * (1.f / 24.f);
    float f5 = maj5 * (1.f / 25.f);
    float f6 = 1.f - ent5 * invlogC;
    float f7 = var5;

    int p = b * HW + (y0 + ly) * Wd + (x0 + lx);
    float4* o = (float4*)(fout + (size_t)p * 8);
    o[0] = make_float4(f0, f1, f2, f3);
    o[1] = make_float4(f4, f5, f6, f7);
}

// ---------------- Kernel A2: per-batch moments of f (8 + 36) ----------------
__global__ __launch_bounds__(256) void kA2(const float* __restrict__ f,
                                           double* __restrict__ stats) {
    // grid: 72 blocks = 8 batches x 9 sub-blocks; each block covers 16384 px
    const int blk = blockIdx.x;
    const int b = blk / 9, sub = blk % 9;
    const int base = b * HW + sub * 16384;
    const int tid = threadIdx.x;

    float s[8];
    float q[36];
    #pragma unroll
    for (int i = 0; i < 8; i++) s[i] = 0.f;
    #pragma unroll
    for (int i = 0; i < 36; i++) q[i] = 0.f;

    for (int j = 0; j < 64; j++) {
        int p = base + j * 256 + tid;
        const float4* fv = (const float4*)(f + (size_t)p * 8);
        float4 a = fv[0], c4 = fv[1];
        float fl[8] = {a.x, a.y, a.z, a.w, c4.x, c4.y, c4.z, c4.w};
        int idx = 0;
        #pragma unroll
        for (int c = 0; c < 8; c++) {
            s[c] += fl[c];
            #pragma unroll
            for (int cp = c; cp < 8; cp++) { q[idx] += fl[c] * fl[cp]; idx++; }
        }
    }

    // wave reduce (width 64)
    #pragma unroll
    for (int c = 0; c < 8; c++)
        for (int o = 32; o >= 1; o >>= 1) s[c] += __shfl_xor(s[c], o);
    #pragma unroll
    for (int i = 0; i < 36; i++)
        for (int o = 32; o >= 1; o >>= 1) q[i] += __shfl_xor(q[i], o);

    __shared__ float red[4][44];
    int lane = tid & 63, wv = tid >> 6;
    if (lane == 0) {
        #pragma unroll
        for (int c = 0; c < 8; c++) red[wv][c] = s[c];
        #pragma unroll
        for (int i = 0; i < 36; i++) red[wv][8 + i] = q[i];
    }
    __syncthreads();
    if (tid < 44) {
        float tot = red[0][tid] + red[1][tid] + red[2][tid] + red[3][tid];
        atomicAdd(&stats[b * 44 + tid], (double)tot);
    }
}

// ---------------- Kernel B: analytic GroupNorm scale/shift ----------------
__global__ __launch_bounds__(512) void kB(const double* __restrict__ stats,
                                          const float* __restrict__ W1,
                                          const float* __restrict__ b1,
                                          const float* __restrict__ gnw,
                                          const float* __restrict__ gnb,
                                          float* __restrict__ ga,
                                          float* __restrict__ gb) {
    const int tid = threadIdx.x;
    const int b = tid >> 6, d = tid & 63;
    const double* st = stats + b * 44;
    const double invN = 1.0 / (double)HW;

    double m[8];
    #pragma unroll
    for (int c = 0; c < 8; c++) m[c] = st[c] * invN;
    double w[8];
    #pragma unroll
    for (int c = 0; c < 8; c++) w[c] = (double)W1[d * 8 + c];

    double wv = 0.0;
    #pragma unroll
    for (int c = 0; c < 8; c++) wv += w[c] * m[c];

    double quad = 0.0;
    int idx = 8;
    #pragma unroll
    for (int c = 0; c < 8; c++) {
        #pragma unroll
        for (int cp = c; cp < 8; cp++) {
            double e2 = st[idx] * invN; idx++;
            quad += (c == cp ? 1.0 : 2.0) * w[c] * w[cp] * e2;
        }
    }
    double bb  = (double)b1[d];
    double mu  = wv + bb;                       // E[h_d]
    double eh2 = quad + 2.0 * bb * wv + bb * bb; // E[h_d^2]

    // reduce over the 8 channels of the group (consecutive lanes)
    double gm = mu, gq = eh2;
    #pragma unroll
    for (int o = 1; o < 8; o <<= 1) { gm += __shfl_xor(gm, o); gq += __shfl_xor(gq, o); }
    gm *= 0.125; gq *= 0.125;
    double var = gq - gm * gm;
    double rs  = rsqrt(var + 1e-5);

    float A  = (float)rs * gnw[d];
    float Bs = gnb[d] - (float)(gm * rs) * gnw[d];
    ga[tid] = A;
    gb[tid] = Bs;
}

// ---------------- Kernel C: 1x1conv -> GN affine -> GELU -> 1x1conv --------
__global__ __launch_bounds__(256) void kC(const float* __restrict__ f,
                                          const float* __restrict__ W1,
                                          const float* __restrict__ b1,
                                          const float* __restrict__ W2,
                                          const float* __restrict__ b2,
                                          const float* __restrict__ ga,
                                          const float* __restrict__ gb,
                                          float* __restrict__ out) {
    const int b   = blockIdx.x / BLOCKS_PER_IMG;            // uniform
    const int pix = (blockIdx.x % BLOCKS_PER_IMG) * 256 + threadIdx.x;
    const int p   = b * HW + pix;

    const float4* fv = (const float4*)(f + (size_t)p * 8);
    float4 a = fv[0], c4 = fv[1];
    float fl[8] = {a.x, a.y, a.z, a.w, c4.x, c4.y, c4.z, c4.w};

    float g[64];
    #pragma unroll
    for (int d = 0; d < 64; d++) {
        float h = b1[d];
        #pragma unroll
        for (int c = 0; c < 8; c++) h += W1[d * 8 + c] * fl[c];
        h = h * ga[b * 64 + d] + gb[b * 64 + d];
        g[d] = 0.5f * h * (1.0f + erff(h * 0.70710678118f));
    }

    float* ob = out + (size_t)b * 64 * HW + pix;
    #pragma unroll 4
    for (int e = 0; e < 64; e++) {
        float acc = b2[e];
        #pragma unroll
        for (int d = 0; d < 64; d++) acc += W2[e * 64 + d] * g[d];
        ob[(size_t)e * HW] = acc;
    }
}

extern "C" void kernel_launch(void* const* d_in, const int* in_sizes, int n_in,
                              void* d_out, int out_size, void* d_ws, size_t ws_size,
                              hipStream_t stream) {
    const float* x   = (const float*)d_in[0];
    const float* W1  = (const float*)d_in[1];
    const float* b1  = (const float*)d_in[2];
    const float* gnw = (const float*)d_in[3];
    const float* gnb = (const float*)d_in[4];
    const float* W2  = (const float*)d_in[5];
    const float* b2  = (const float*)d_in[6];
    float* out = (float*)d_out;

    char* ws = (char*)d_ws;
    const size_t FBYTES = (size_t)Bn * HW * 8 * sizeof(float); // 37,748,736
    float*  fbuf  = (float*)ws;
    double* stats = (double*)(ws + FBYTES);                    // 8*44 doubles
    float*  ga    = (float*)(ws + FBYTES + 8 * 44 * sizeof(double));
    float*  gbuf  = ga + Bn * 64;

    hipMemsetAsync(stats, 0, 8 * 44 * sizeof(double), stream);
    kA<<<Bn * BLOCKS_PER_IMG, 256, 0, stream>>>(x, fbuf);
    kA2<<<72, 256, 0, stream>>>(fbuf, stats);
    kB<<<1, 512, 0, stream>>>(stats, W1, b1, gnw, gnb, ga, gbuf);
    kC<<<Bn * BLOCKS_PER_IMG, 256, 0, stream>>>(fbuf, W1, b1, W2, b2, ga, gbuf, out);
}

// Round 2
// 427.148 us; speedup vs baseline: 2.1339x; 2.1339x over previous
//
#include <hip/hip_runtime.h>
#include <math.h>

#define Bn 8
#define Cn 10
#define Hd 384
#define Wd 384
#define HW (Hd*Wd)          // 147456
#define TX 32
#define TY 8
#define TLX 36              // TX + 4 halo
#define TLY 12              // TY + 4 halo
#define TSZ (TLX*TLY)       // 432
#define BLOCKS_PER_IMG 576  // HW/256
#define TILES_X 12          // 384/32

typedef __attribute__((ext_vector_type(8))) short s8v;   // 8 x bf16 (4 VGPRs)
typedef __attribute__((ext_vector_type(4))) float f4v;   // MFMA C/D

__device__ __forceinline__ unsigned short f2bf(float f) {
    unsigned u = __builtin_bit_cast(unsigned, f);
    u += 0x7fffu + ((u >> 16) & 1u);           // RNE (values are finite)
    return (unsigned short)(u >> 16);
}

// Branchless erf-GELU, Abramowitz-Stegun 7.1.26 (|err| <= 1.5e-7)
__device__ __forceinline__ float gelu_erf(float h) {
    float z  = 0.70710678118654752f * h;
    float az = fabsf(z);
    float t  = __builtin_amdgcn_rcpf(1.0f + 0.3275911f * az);
    float poly = ((((1.061405429f * t - 1.453152027f) * t + 1.421413741f) * t
                   - 0.284496736f) * t + 0.254829592f) * t;
    float e = __expf(-az * az);
    float erf_z = copysignf(1.0f - poly * e, z);
    return 0.5f * h * (1.0f + erf_z);
}

// ---------------- Kernel A: softmax + neighborhood features ----------------
__global__ __launch_bounds__(256) void kA(const float* __restrict__ x,
                                          float* __restrict__ fout) {
    __shared__ float Pt[Cn * TSZ];
    const int bid = blockIdx.x;
    const int b   = bid / BLOCKS_PER_IMG;
    const int t   = bid % BLOCKS_PER_IMG;
    const int ty  = t / TILES_X, tx = t % TILES_X;
    const int x0  = tx * TX, y0 = ty * TY;
    const int tid = threadIdx.x;
    const float* xb = x + b * Cn * HW;

    for (int i = tid; i < TSZ; i += 256) {
        int ly = i / TLX, lx = i % TLX;
        int gy = y0 + ly - 2; gy = max(0, min(Hd - 1, gy));
        int gx = x0 + lx - 2; gx = max(0, min(Wd - 1, gx));
        const float* px = xb + gy * Wd + gx;
        float v[Cn];
        float m = -1e30f;
        #pragma unroll
        for (int c = 0; c < Cn; c++) { v[c] = px[c * HW]; m = fmaxf(m, v[c]); }
        float s = 0.f;
        #pragma unroll
        for (int c = 0; c < Cn; c++) { v[c] = __expf(v[c] - m); s += v[c]; }
        float inv = 1.0f / s;
        #pragma unroll
        for (int c = 0; c < Cn; c++) Pt[c * TSZ + i] = v[c] * inv;
    }
    __syncthreads();

    const int lx = tid % TX, ly = tid / TX;
    float match3 = 0.f, ent3 = 0.f, var3 = 0.f, maj3 = -1e30f;
    float match5 = 0.f, ent5 = 0.f, var5 = 0.f, maj5 = -1e30f;

    #pragma unroll 1
    for (int c = 0; c < Cn; c++) {
        const float* Pc = &Pt[c * TSZ + (ly + 2) * TLX + (lx + 2)];
        float S5 = 0.f, S3 = 0.f, Q5 = 0.f, Q3 = 0.f;
        #pragma unroll
        for (int dy = -2; dy <= 2; dy++) {
            #pragma unroll
            for (int dx = -2; dx <= 2; dx++) {
                float v = Pc[dy * TLX + dx];
                S5 += v; Q5 += v * v;
                if (dy >= -1 && dy <= 1 && dx >= -1 && dx <= 1) {
                    S3 += v; Q3 += v * v;
                }
            }
        }
        float pc = Pc[0];
        match3 += pc * (S3 - pc);
        match5 += pc * (S5 - pc);
        maj3 = fmaxf(maj3, S3);
        maj5 = fmaxf(maj5, S5);
        float q3 = fmaxf(S3 * (1.f / 9.f), 1e-8f);  ent3 -= q3 * __logf(q3);
        float q5 = fmaxf(S5 * (1.f / 25.f), 1e-8f); ent5 -= q5 * __logf(q5);
        float pb3 = S3 * (1.f / 9.f);  var3 += Q3 * (1.f / 9.f)  - pb3 * pb3;
        float pb5 = S5 * (1.f / 25.f); var5 += Q5 * (1.f / 25.f) - pb5 * pb5;
    }

    const float invlogC = 1.0f / 2.302585092994046f;
    float f0 = match3 * (1.f / 8.f);
    float f1 = maj3 * (1.f / 9.f);
    float f2 = 1.f - ent3 * invlogC;
    float f3 = var3;
    float f4 = match5 * (1.f / 24.f);
    float f5 = maj5 * (1.f / 25.f);
    float f6 = 1.f - ent5 * invlogC;
    float f7 = var5;

    int p = b * HW + (y0 + ly) * Wd + (x0 + lx);
    float4* o = (float4*)(fout + (size_t)p * 8);
    o[0] = make_float4(f0, f1, f2, f3);
    o[1] = make_float4(f4, f5, f6, f7);
}

// ---------------- Kernel A2: per-batch moments of f (8 + 36) ----------------
__global__ __launch_bounds__(256) void kA2(const float* __restrict__ f,
                                           double* __restrict__ stats) {
    const int blk = blockIdx.x;
    const int b = blk / 9, sub = blk % 9;
    const int base = b * HW + sub * 16384;
    const int tid = threadIdx.x;

    float s[8];
    float q[36];
    #pragma unroll
    for (int i = 0; i < 8; i++) s[i] = 0.f;
    #pragma unroll
    for (int i = 0; i < 36; i++) q[i] = 0.f;

    for (int j = 0; j < 64; j++) {
        int p = base + j * 256 + tid;
        const float4* fv = (const float4*)(f + (size_t)p * 8);
        float4 a = fv[0], c4 = fv[1];
        float fl[8] = {a.x, a.y, a.z, a.w, c4.x, c4.y, c4.z, c4.w};
        int idx = 0;
        #pragma unroll
        for (int c = 0; c < 8; c++) {
            s[c] += fl[c];
            #pragma unroll
            for (int cp = c; cp < 8; cp++) { q[idx] += fl[c] * fl[cp]; idx++; }
        }
    }

    #pragma unroll
    for (int c = 0; c < 8; c++)
        for (int o = 32; o >= 1; o >>= 1) s[c] += __shfl_xor(s[c], o);
    #pragma unroll
    for (int i = 0; i < 36; i++)
        for (int o = 32; o >= 1; o >>= 1) q[i] += __shfl_xor(q[i], o);

    __shared__ float red[4][44];
    int lane = tid & 63, wv = tid >> 6;
    if (lane == 0) {
        #pragma unroll
        for (int c = 0; c < 8; c++) red[wv][c] = s[c];
        #pragma unroll
        for (int i = 0; i < 36; i++) red[wv][8 + i] = q[i];
    }
    __syncthreads();
    if (tid < 44) {
        float tot = red[0][tid] + red[1][tid] + red[2][tid] + red[3][tid];
        atomicAdd(&stats[b * 44 + tid], (double)tot);
    }
}

// ---------------- Kernel B: analytic GroupNorm scale/shift ----------------
__global__ __launch_bounds__(512) void kB(const double* __restrict__ stats,
                                          const float* __restrict__ W1,
                                          const float* __restrict__ b1,
                                          const float* __restrict__ gnw,
                                          const float* __restrict__ gnb,
                                          float* __restrict__ ga,
                                          float* __restrict__ gb) {
    const int tid = threadIdx.x;
    const int b = tid >> 6, d = tid & 63;
    const double* st = stats + b * 44;
    const double invN = 1.0 / (double)HW;

    double m[8];
    #pragma unroll
    for (int c = 0; c < 8; c++) m[c] = st[c] * invN;
    double w[8];
    #pragma unroll
    for (int c = 0; c < 8; c++) w[c] = (double)W1[d * 8 + c];

    double wv = 0.0;
    #pragma unroll
    for (int c = 0; c < 8; c++) wv += w[c] * m[c];

    double quad = 0.0;
    int idx = 8;
    #pragma unroll
    for (int c = 0; c < 8; c++) {
        #pragma unroll
        for (int cp = c; cp < 8; cp++) {
            double e2 = st[idx] * invN; idx++;
            quad += (c == cp ? 1.0 : 2.0) * w[c] * w[cp] * e2;
        }
    }
    double bb  = (double)b1[d];
    double mu  = wv + bb;
    double eh2 = quad + 2.0 * bb * wv + bb * bb;

    double gm = mu, gq = eh2;
    #pragma unroll
    for (int o = 1; o < 8; o <<= 1) { gm += __shfl_xor(gm, o); gq += __shfl_xor(gq, o); }
    gm *= 0.125; gq *= 0.125;
    double var = gq - gm * gm;
    double rs  = rsqrt(var + 1e-5);

    float A  = (float)rs * gnw[d];
    float Bs = gnb[d] - (float)(gm * rs) * gnw[d];
    ga[tid] = A;
    gb[tid] = Bs;
}

// ------- Kernel C2: 1x1conv -> GN affine -> GELU -> MFMA 1x1conv -----------
// Block = 256 threads = 4 waves = 256 pixels. Layer2 via 16x16x32 bf16 MFMA.
// LDS layout: g_lds[px][d], row stride 33 dwords (66 bf16) -> 2-way write
// conflicts (free), <=4-way on the b32 b-frag reads.
__global__ __launch_bounds__(256) void kC2(const float* __restrict__ f,
                                           const float* __restrict__ W1,
                                           const float* __restrict__ b1,
                                           const float* __restrict__ W2,
                                           const float* __restrict__ b2,
                                           const float* __restrict__ ga,
                                           const float* __restrict__ gb,
                                           float* __restrict__ out) {
    __shared__ unsigned gl[256 * 33];
    const int b    = blockIdx.x / BLOCKS_PER_IMG;
    const int tile = blockIdx.x % BLOCKS_PER_IMG;
    const int pix0 = tile * 256;
    const int tid  = threadIdx.x;

    // ---- phase 1: per-thread pixel -> h[64] -> GN affine -> GELU -> LDS ----
    {
        const float4* fv = (const float4*)(f + ((size_t)(b * HW + pix0 + tid)) * 8);
        float4 A = fv[0], Bv = fv[1];
        float fl[8] = {A.x, A.y, A.z, A.w, Bv.x, Bv.y, Bv.z, Bv.w};
        const float* gaB = ga + b * 64;
        const float* gbB = gb + b * 64;
        unsigned* row = &gl[tid * 33];
        #pragma unroll
        for (int d2 = 0; d2 < 32; d2++) {
            float h0 = b1[2 * d2], h1 = b1[2 * d2 + 1];
            #pragma unroll
            for (int c = 0; c < 8; c++) {
                h0 += W1[(2 * d2) * 8 + c] * fl[c];
                h1 += W1[(2 * d2 + 1) * 8 + c] * fl[c];
            }
            h0 = h0 * gaB[2 * d2]     + gbB[2 * d2];
            h1 = h1 * gaB[2 * d2 + 1] + gbB[2 * d2 + 1];
            float g0 = gelu_erf(h0), g1 = gelu_erf(h1);
            row[d2] = (unsigned)f2bf(g0) | ((unsigned)f2bf(g1) << 16);
        }
    }
    __syncthreads();

    // ---- phase 2: out[e,px] = W2[e,:] . g[:,px] + b2 via MFMA ----
    const int w    = tid >> 6;
    const int lane = tid & 63;
    const int quad = lane >> 4;
    const int col  = lane & 15;

    // A fragments: A[m=lane&15][k=quad*8+j] = W2[e0+m][k0+quad*8+j]
    s8v afr[4][2];
    #pragma unroll
    for (int u = 0; u < 4; u++) {
        const float* wr = W2 + (size_t)(16 * u + col) * 64 + quad * 8;
        #pragma unroll
        for (int kc = 0; kc < 2; kc++) {
            const float4* w4 = (const float4*)(wr + 32 * kc);
            float4 x0 = w4[0], x1 = w4[1];
            union { unsigned short us[8]; s8v v; } cv;
            cv.us[0] = f2bf(x0.x); cv.us[1] = f2bf(x0.y);
            cv.us[2] = f2bf(x0.z); cv.us[3] = f2bf(x0.w);
            cv.us[4] = f2bf(x1.x); cv.us[5] = f2bf(x1.y);
            cv.us[6] = f2bf(x1.z); cv.us[7] = f2bf(x1.w);
            afr[u][kc] = cv.v;
        }
    }

    // init acc with b2 (C/D: row e = 16u + quad*4 + r, col px)
    f4v acc[4][4];
    #pragma unroll
    for (int u = 0; u < 4; u++) {
        float b2r[4];
        #pragma unroll
        for (int r = 0; r < 4; r++) b2r[r] = b2[16 * u + quad * 4 + r];
        #pragma unroll
        for (int t = 0; t < 4; t++) {
            f4v a0; a0[0] = b2r[0]; a0[1] = b2r[1]; a0[2] = b2r[2]; a0[3] = b2r[3];
            acc[u][t] = a0;
        }
    }

    #pragma unroll
    for (int kc = 0; kc < 2; kc++) {
        s8v bfr[4];
        #pragma unroll
        for (int t = 0; t < 4; t++) {
            int px = 64 * w + 16 * t + col;
            const unsigned* r = &gl[px * 33 + kc * 16 + quad * 4];
            union { unsigned u[4]; s8v v; } cv;
            cv.u[0] = r[0]; cv.u[1] = r[1]; cv.u[2] = r[2]; cv.u[3] = r[3];
            bfr[t] = cv.v;
        }
        #pragma unroll
        for (int u = 0; u < 4; u++)
            #pragma unroll
            for (int t = 0; t < 4; t++)
                acc[u][t] = __builtin_amdgcn_mfma_f32_16x16x32_bf16(
                    afr[u][kc], bfr[t], acc[u][t], 0, 0, 0);
    }

    // ---- store ----
    float* ob = out + (size_t)b * 64 * HW + pix0;
    #pragma unroll
    for (int u = 0; u < 4; u++) {
        #pragma unroll
        for (int t = 0; t < 4; t++) {
            int px = 64 * w + 16 * t + col;
            #pragma unroll
            for (int r = 0; r < 4; r++) {
                int e = 16 * u + quad * 4 + r;
                ob[(size_t)e * HW + px] = acc[u][t][r];
            }
        }
    }
}

extern "C" void kernel_launch(void* const* d_in, const int* in_sizes, int n_in,
                              void* d_out, int out_size, void* d_ws, size_t ws_size,
                              hipStream_t stream) {
    const float* x   = (const float*)d_in[0];
    const float* W1  = (const float*)d_in[1];
    const float* b1  = (const float*)d_in[2];
    const float* gnw = (const float*)d_in[3];
    const float* gnb = (const float*)d_in[4];
    const float* W2  = (const float*)d_in[5];
    const float* b2  = (const float*)d_in[6];
    float* out = (float*)d_out;

    char* ws = (char*)d_ws;
    const size_t FBYTES = (size_t)Bn * HW * 8 * sizeof(float); // 37,748,736
    float*  fbuf  = (float*)ws;
    double* stats = (double*)(ws + FBYTES);
    float*  ga    = (float*)(ws + FBYTES + 8 * 44 * sizeof(double));
    float*  gbuf  = ga + Bn * 64;

    hipMemsetAsync(stats, 0, 8 * 44 * sizeof(double), stream);
    kA<<<Bn * BLOCKS_PER_IMG, 256, 0, stream>>>(x, fbuf);
    kA2<<<72, 256, 0, stream>>>(fbuf, stats);
    kB<<<1, 512, 0, stream>>>(stats, W1, b1, gnw, gnb, ga, gbuf);
    kC2<<<Bn * BLOCKS_PER_IMG, 256, 0, stream>>>(fbuf, W1, b1, W2, b2, ga, gbuf, out);
}